// Round 11
// baseline (383.874 us; speedup 1.0000x reference)
//
#include <hip/hip_runtime.h>
#include <hip/hip_cooperative_groups.h>
#include <hip/hip_bf16.h>

namespace cg = cooperative_groups;

// GAT x2 (3 heads, E=2048, batch 0 only) + 2-layer GCN, log_softmax / leaky.
// Non-neighbor exp(-30) terms dropped (~1e-10 effect vs threshold 32).
// Phase bodies shared between ONE cooperative mono-kernel (256 blocks x 384
// threads -- guaranteed co-residency at 1 block/CU) and a 7-kernel fallback
// taken if hipLaunchCooperativeKernel returns an error (R10: 512-block coop
// launch silently refused; ALWAYS check the return code).
// No atomics (uncached 16B RMW, R6). Split-K partials + inline merges.

#define NB 256   // grid blocks (fixed for phase decompositions)
#define NT 384   // threads/block (6 waves)

// ---------------------------------------------------------------------------
// P0: bitmask (waves 0-3, 8 rows/block) + features (wave 4, 16 nodes/block).
__device__ __forceinline__ void phase0(
    int b, int tid, const float* __restrict__ adj0, unsigned int* __restrict__ bm,
    const float* __restrict__ node, const float* __restrict__ uv,
    const float* __restrict__ Wt1, const float* __restrict__ at1,
    const float* __restrict__ Wt2, const float* __restrict__ at2,
    float* __restrict__ hcol, float4* __restrict__ pk1q, float* __restrict__ pack2) {
  int w6 = tid >> 6, lane = tid & 63;
  if (w6 < 4) {
#pragma unroll
    for (int rep = 0; rep < 2; ++rep) {
      int row = b * 8 + rep * 4 + w6;
      const float* arow = adj0 + (size_t)row * 2048;
#pragma unroll 4
      for (int it = 0; it < 32; ++it) {
        float v = arow[it * 64 + lane];
        unsigned long long mask = __ballot(v == 1.0f);
        if (lane == 0) bm[row * 64 + it * 2] = (unsigned int)mask;
        else if (lane == 32) bm[row * 64 + it * 2 + 1] = (unsigned int)(mask >> 32);
      }
    }
  }
  if (tid >= 256 && tid < 272) {
    int unit = b * 16 + (tid - 256);   // 4096 units = 2 gat x 2048 nodes
    int g = unit >> 11;
    int e = unit & 2047;
    const float* W = g ? Wt2 : Wt1;
    const float* A = g ? at2 : at1;
    const float* x = (g ? uv : node) + e * 32;
    float xv[32];
#pragma unroll
    for (int i = 0; i < 32; ++i) xv[i] = x[i];
#pragma unroll
    for (int h = 0; h < 3; ++h) {
      float hv[6];
#pragma unroll
      for (int d = 0; d < 6; ++d) hv[d] = 0.f;
#pragma unroll
      for (int i = 0; i < 32; ++i)
#pragma unroll
        for (int d = 0; d < 6; ++d) hv[d] += xv[i] * W[h * 192 + i * 6 + d];
      float e1 = 0.f, e2 = 0.f;
#pragma unroll
      for (int d = 0; d < 6; ++d) {
        e1 += hv[d] * A[h * 12 + d];
        e2 += hv[d] * A[h * 12 + 6 + d];
      }
      int c = g * 3 + h;
#pragma unroll
      for (int d = 0; d < 6; ++d) hcol[(c * 6 + d) * 2048 + e] = hv[d];
      pk1q[c * 2048 + e] = make_float4(e1, __expf(e1), __expf(0.2f * e1), 0.f);
      pack2[c * 2048 + e] = e2;
      pack2[(6 + c) * 2048 + e] = __expf(e2);
      pack2[(12 + c) * 2048 + e] = __expf(0.2f * e2);
    }
  }
}

// ---------------------------------------------------------------------------
// P1: rowsums + scaled-h. Wave = comp c (6 waves), 8 rows/block.
__device__ __forceinline__ void phase1(
    int b, int tid, const unsigned int* __restrict__ bm,
    const float4* __restrict__ pk1q, const float* __restrict__ pack2,
    const float* __restrict__ hcol, float* __restrict__ hs8) {
  int c = tid >> 6, lane = tid & 63;
  int i0 = b * 8;
  const float4* p2_4 = (const float4*)pack2;
  float e1r[8], p1r[8], q1r[8], sum[8];
#pragma unroll
  for (int r = 0; r < 8; ++r) {
    float4 pq = pk1q[c * 2048 + i0 + r];
    e1r[r] = pq.x; p1r[r] = pq.y; q1r[r] = pq.z;
    sum[r] = 0.f;
  }
  int sh = (lane & 7) * 4;
#pragma unroll
  for (int it = 0; it < 8; ++it) {
    int j4 = it * 64 + lane;
    float4 e2 = p2_4[c * 512 + j4];
    float4 p2 = p2_4[(6 + c) * 512 + j4];
    float4 q2 = p2_4[(12 + c) * 512 + j4];
    int wbase = it * 8 + (lane >> 3);
    float abx, aby, abz, abw;
#pragma unroll
    for (int r = 0; r < 8; ++r) {
      unsigned int wd = bm[(i0 + r) * 64 + wbase] >> sh;
      { float e = e1r[r] + e2.x; bool p = e > 0.f;
        abx = (p ? p1r[r] : q1r[r]) * (p ? p2.x : q2.x); }
      { float e = e1r[r] + e2.y; bool p = e > 0.f;
        aby = (p ? p1r[r] : q1r[r]) * (p ? p2.y : q2.y); }
      { float e = e1r[r] + e2.z; bool p = e > 0.f;
        abz = (p ? p1r[r] : q1r[r]) * (p ? p2.z : q2.z); }
      { float e = e1r[r] + e2.w; bool p = e > 0.f;
        abw = (p ? p1r[r] : q1r[r]) * (p ? p2.w : q2.w); }
      float s = ((wd & 1u) ? abx : 0.f) + ((wd & 2u) ? aby : 0.f) +
                ((wd & 4u) ? abz : 0.f) + ((wd & 8u) ? abw : 0.f);
      sum[r] += s;
    }
  }
#pragma unroll
  for (int r = 0; r < 8; ++r) {
#pragma unroll
    for (int off = 32; off > 0; off >>= 1) sum[r] += __shfl_down(sum[r], off);
  }
  float s0 = __shfl(sum[0], 0), s1 = __shfl(sum[1], 0);
  float s2 = __shfl(sum[2], 0), s3 = __shfl(sum[3], 0);
  float s4 = __shfl(sum[4], 0), s5 = __shfl(sum[5], 0);
  float s6 = __shfl(sum[6], 0), s7 = __shfl(sum[7], 0);
  int r = lane >> 3, d = lane & 7;
  float sv = r < 4 ? (r < 2 ? (r == 0 ? s0 : s1) : (r == 2 ? s2 : s3))
                   : (r < 6 ? (r == 4 ? s4 : s5) : (r == 6 ? s6 : s7));
  float v = (d < 6) ? hcol[(c * 6 + d) * 2048 + i0 + r] * (1.0f / sv) : 0.f;
  hs8[((size_t)c * 2048 + i0 + r) * 8 + d] = v;
}

// ---------------------------------------------------------------------------
// P2: h' partials, LDS-free (wave = comp, 2 j/thread, 128 i rows).
// Grid decomp: 16 j-tiles x 16 i-splits. hp_part has 16 partials.
__device__ __forceinline__ void phase2(
    int b, int tid, const unsigned int* __restrict__ bm,
    const float4* __restrict__ pk1q, const float* __restrict__ pack2,
    const float4* __restrict__ hs8_4, float* __restrict__ hp_part) {
  int c6 = tid >> 6, jl = tid & 63;
  int j0 = (b & 15) * 128;
  int i0 = (b >> 4) * 128;
  int jA = j0 + jl, jB = jA + 64;
  float e2A = pack2[c6 * 2048 + jA];
  float p2A = pack2[(6 + c6) * 2048 + jA];
  float q2A = pack2[(12 + c6) * 2048 + jA];
  float e2B = pack2[c6 * 2048 + jB];
  float p2B = pack2[(6 + c6) * 2048 + jB];
  float q2B = pack2[(12 + c6) * 2048 + jB];
  float aA0 = 0.f, aA1 = 0.f, aA2 = 0.f, aA3 = 0.f, aA4 = 0.f, aA5 = 0.f;
  float aB0 = 0.f, aB1 = 0.f, aB2 = 0.f, aB3 = 0.f, aB4 = 0.f, aB5 = 0.f;
  int hi = jl >> 5;
  int shj = jl & 31;
  const float4* pk1 = pk1q + c6 * 2048;
  const float4* hs = hs8_4 + (size_t)c6 * 2048 * 2;
  const unsigned int* bmA = bm + (size_t)i0 * 64 + (j0 >> 5) + hi;
#pragma unroll 4
  for (int ii = 0; ii < 128; ++ii) {
    int irow = i0 + ii;
    float4 pk = pk1[irow];
    float4 h0 = hs[irow * 2];
    float4 h1 = hs[irow * 2 + 1];
    unsigned int wdA = bmA[ii * 64];
    unsigned int wdB = bmA[ii * 64 + 2];
    {
      float e = pk.x + e2A; bool p = e > 0.f;
      float ab = (p ? pk.y : pk.z) * (p ? p2A : q2A);
      float wg = ((wdA >> shj) & 1u) ? ab : 0.f;
      aA0 += wg * h0.x; aA1 += wg * h0.y; aA2 += wg * h0.z;
      aA3 += wg * h0.w; aA4 += wg * h1.x; aA5 += wg * h1.y;
    }
    {
      float e = pk.x + e2B; bool p = e > 0.f;
      float ab = (p ? pk.y : pk.z) * (p ? p2B : q2B);
      float wg = ((wdB >> shj) & 1u) ? ab : 0.f;
      aB0 += wg * h0.x; aB1 += wg * h0.y; aB2 += wg * h0.z;
      aB3 += wg * h0.w; aB4 += wg * h1.x; aB5 += wg * h1.y;
    }
  }
  float* hp = hp_part + (size_t)(b >> 4) * 73728;
  int kb = c6 * 6;
  hp[(kb + 0) * 2048 + jA] = aA0;
  hp[(kb + 1) * 2048 + jA] = aA1;
  hp[(kb + 2) * 2048 + jA] = aA2;
  hp[(kb + 3) * 2048 + jA] = aA3;
  hp[(kb + 4) * 2048 + jA] = aA4;
  hp[(kb + 5) * 2048 + jA] = aA5;
  hp[(kb + 0) * 2048 + jB] = aB0;
  hp[(kb + 1) * 2048 + jB] = aB1;
  hp[(kb + 2) * 2048 + jB] = aB2;
  hp[(kb + 3) * 2048 + jB] = aB3;
  hp[(kb + 4) * 2048 + jB] = aB4;
  hp[(kb + 5) * 2048 + jB] = aB5;
}

// ---------------------------------------------------------------------------
// P3: merge 16 hp partials -> elu -> T[j][32]. 8 j/block. smem >= 2896 B.
__device__ __forceinline__ void phase3(
    int b, int tid, char* smem, const float* __restrict__ hp_part,
    const float* __restrict__ Wg1, const float* __restrict__ Wo1,
    float* __restrict__ T) {
  float* sHP = (float*)smem;     // 8*37 = 296
  float* sWg = sHP + 296;        // 288
  float* sWo = sWg + 288;        // 288
  int j0 = b * 8;
  for (int idx = tid; idx < 288; idx += NT) {
    sWg[idx] = Wg1[idx];
    sWo[idx] = Wo1[idx];
  }
  for (int idx = tid; idx < 288; idx += NT) {
    int r = idx >> 3, jl = idx & 7;
    float s = 0.f;
#pragma unroll
    for (int sp = 0; sp < 16; ++sp)
      s += hp_part[(size_t)sp * 73728 + r * 2048 + j0 + jl];
    sHP[jl * 37 + r] = s > 0.f ? s : __expf(s) - 1.f;
  }
  __syncthreads();
  if (tid < 256) {
    int jl = tid >> 5, col = tid & 31;
    int gat = col >> 4, cc = col & 15;
    const float* Wp = gat ? sWo : sWg;
    float a = 0.f;
#pragma unroll
    for (int r = 0; r < 18; ++r)
      a += sHP[jl * 37 + gat * 18 + r] * Wp[r * 16 + cc];
    T[(j0 + jl) * 32 + col] = a;
  }
  __syncthreads();
}

// ---------------------------------------------------------------------------
// P4: GCN1 split-K -> Craw_part. 32 row-tiles x 8 k-splits of 256 (two
// 128-k LDS stages). smem >= 18432 B. Craw_part has 8 partials.
__device__ __forceinline__ void phase4(
    int b, int tid, char* smem, const unsigned int* __restrict__ bm,
    const float* __restrict__ T, float* __restrict__ Craw_part) {
  unsigned int* sM = (unsigned int*)smem;   // 512 words (2 KB)
  float4* sT4 = (float4*)(smem + 2048);     // 1024 float4 (16 KB)
  const float4* T4 = (const float4*)T;
  int i0 = (b & 31) * 64;
  int k0 = (b >> 5) * 256;
  for (int idx = tid; idx < 512; idx += NT)
    sM[idx] = bm[(size_t)(i0 + (idx >> 3)) * 64 + (k0 >> 5) + (idx & 7)];
  int rl = tid & 31, cg2 = tid >> 5;
  float a0x = 0.f, a0y = 0.f, a0z = 0.f, a0w = 0.f;
  float a1x = 0.f, a1y = 0.f, a1z = 0.f, a1w = 0.f;
#pragma unroll
  for (int st = 0; st < 2; ++st) {
    __syncthreads();
    for (int idx = tid; idx < 1024; idx += NT)
      sT4[idx] = T4[(k0 + st * 128) * 8 + idx];
    __syncthreads();
    if (tid < 256) {
#pragma unroll
      for (int wi = 0; wi < 4; ++wi) {
        unsigned int wA = sM[rl * 8 + st * 4 + wi];
        unsigned int wB = sM[(rl + 32) * 8 + st * 4 + wi];
#pragma unroll 16
        for (int kb = 0; kb < 32; ++kb) {
          float4 t = sT4[(wi * 32 + kb) * 8 + cg2];
          float mA = (float)((wA >> kb) & 1u);
          float mB = (float)((wB >> kb) & 1u);
          a0x += mA * t.x; a0y += mA * t.y; a0z += mA * t.z; a0w += mA * t.w;
          a1x += mB * t.x; a1y += mB * t.y; a1z += mB * t.z; a1w += mB * t.w;
        }
      }
    }
  }
  if (tid < 256) {
    float* base = Craw_part + (size_t)(b >> 5) * 65536;
    *(float4*)&base[(i0 + rl) * 32 + cg2 * 4] = make_float4(a0x, a0y, a0z, a0w);
    *(float4*)&base[(i0 + rl + 32) * 32 + cg2 * 4] = make_float4(a1x, a1y, a1z, a1w);
  }
  __syncthreads();
}

// ---------------------------------------------------------------------------
// P5: merge 8 Craw partials -> bias/relu/@W2 -> T2. 8 j/block.
__device__ __forceinline__ void phase5(
    int b, int tid, const float* __restrict__ Craw_part,
    const float* __restrict__ bg1, const float* __restrict__ Wg2,
    const float* __restrict__ bo1, const float* __restrict__ Wo2,
    float* __restrict__ T2) {
  if (tid >= 256) return;
  int j = b * 8 + (tid >> 5);
  int cl = tid & 31;
  int gat = cl >> 4, cc = cl & 15;
  float x = 0.f;
#pragma unroll
  for (int sp = 0; sp < 8; ++sp)
    x += Craw_part[(size_t)sp * 65536 + j * 32 + cl];
  x += gat ? bo1[cc] : bg1[cc];
  x = x > 0.f ? x : 0.f;
  float pa = x * (gat ? Wo2[cc * 2 + 0] : Wg2[cc * 2 + 0]);
  float pb = x * (gat ? Wo2[cc * 2 + 1] : Wg2[cc * 2 + 1]);
#pragma unroll
  for (int m = 8; m > 0; m >>= 1) {
    pa += __shfl_xor(pa, m);
    pb += __shfl_xor(pb, m);
  }
  if (cc == 0) {
    T2[j * 4 + gat * 2 + 0] = pa;
    T2[j * 4 + gat * 2 + 1] = pb;
  }
}

// ---------------------------------------------------------------------------
// P6: final a0 @ T2 + log_softmax / leaky. 8 rows/block (waves 0-3, 2 reps).
__device__ __forceinline__ void phase6(
    int b, int tid, const unsigned int* __restrict__ bm,
    const float* __restrict__ T2, const float* __restrict__ bg2,
    const float* __restrict__ bo2, float* __restrict__ out) {
  int w6 = tid >> 6, lane = tid & 63;
  if (w6 >= 4) return;
  const float4* T24 = (const float4*)T2;
  int sh = lane & 31;
#pragma unroll
  for (int rep = 0; rep < 2; ++rep) {
    int r = b * 8 + rep * 4 + w6;
    float4 acc = make_float4(0.f, 0.f, 0.f, 0.f);
#pragma unroll 8
    for (int it = 0; it < 32; ++it) {
      int k = it * 64 + lane;
      unsigned int wd = bm[r * 64 + it * 2 + (lane >> 5)];
      float m = (float)((wd >> sh) & 1u);
      float4 t = T24[k];
      acc.x += m * t.x;
      acc.y += m * t.y;
      acc.z += m * t.z;
      acc.w += m * t.w;
    }
#pragma unroll
    for (int off = 32; off > 0; off >>= 1) {
      acc.x += __shfl_down(acc.x, off);
      acc.y += __shfl_down(acc.y, off);
      acc.z += __shfl_down(acc.z, off);
      acc.w += __shfl_down(acc.w, off);
    }
    if (lane == 0) {
      float y0 = acc.x + bg2[0], y1 = acc.y + bg2[1];
      float m = fmaxf(y0, y1);
      float ls = m + logf(__expf(y0 - m) + __expf(y1 - m));
      out[r * 2 + 0] = y0 - ls;
      out[r * 2 + 1] = y1 - ls;
      float o0 = acc.z + bo2[0], o1 = acc.w + bo2[1];
      out[4096 + r * 2 + 0] = o0 > 0.f ? o0 : 0.01f * o0;
      out[4096 + r * 2 + 1] = o1 > 0.f ? o1 : 0.01f * o1;
    }
  }
}

// ---------------------------------------------------------------------------
// Mono cooperative kernel: 256 blocks x 384 threads, 6 grid.sync().
__global__ __launch_bounds__(NT, 2) void gat_gcn_mono(
    const float* adj0, unsigned int* bm, const float* node, const float* uv,
    const float* Wt1, const float* at1, const float* Wt2, const float* at2,
    float* hcol, float4* pk1q, float* pack2, float* hs8, float* hp_part,
    const float* Wg1, const float* Wo1, float* T, float* Craw_part,
    const float* bg1, const float* Wg2, const float* bo1, const float* Wo2,
    float* T2, const float* bg2, const float* bo2, float* out) {
  cg::grid_group grid = cg::this_grid();
  __shared__ __align__(16) char smem[18432];
  int b = blockIdx.x, tid = threadIdx.x;
  phase0(b, tid, adj0, bm, node, uv, Wt1, at1, Wt2, at2, hcol, pk1q, pack2);
  grid.sync();
  phase1(b, tid, bm, pk1q, pack2, hcol, hs8);
  grid.sync();
  phase2(b, tid, bm, pk1q, pack2, (const float4*)hs8, hp_part);
  grid.sync();
  phase3(b, tid, smem, hp_part, Wg1, Wo1, T);
  grid.sync();
  phase4(b, tid, smem, bm, T, Craw_part);
  grid.sync();
  phase5(b, tid, Craw_part, bg1, Wg2, bo1, Wo2, T2);
  grid.sync();
  phase6(b, tid, bm, T2, bg2, bo2, out);
}

// ---------------------------------------------------------------------------
// Fallback: identical phase bodies as 7 ordinary kernels.
__global__ __launch_bounds__(NT, 2) void f0(
    const float* adj0, unsigned int* bm, const float* node, const float* uv,
    const float* Wt1, const float* at1, const float* Wt2, const float* at2,
    float* hcol, float4* pk1q, float* pack2) {
  phase0(blockIdx.x, threadIdx.x, adj0, bm, node, uv, Wt1, at1, Wt2, at2,
         hcol, pk1q, pack2);
}
__global__ __launch_bounds__(NT, 2) void f1(
    const unsigned int* bm, const float4* pk1q, const float* pack2,
    const float* hcol, float* hs8) {
  phase1(blockIdx.x, threadIdx.x, bm, pk1q, pack2, hcol, hs8);
}
__global__ __launch_bounds__(NT, 2) void f2(
    const unsigned int* bm, const float4* pk1q, const float* pack2,
    const float4* hs8_4, float* hp_part) {
  phase2(blockIdx.x, threadIdx.x, bm, pk1q, pack2, hs8_4, hp_part);
}
__global__ __launch_bounds__(NT, 2) void f3(
    const float* hp_part, const float* Wg1, const float* Wo1, float* T) {
  __shared__ __align__(16) char smem[3584];
  phase3(blockIdx.x, threadIdx.x, smem, hp_part, Wg1, Wo1, T);
}
__global__ __launch_bounds__(NT, 2) void f4(
    const unsigned int* bm, const float* T, float* Craw_part) {
  __shared__ __align__(16) char smem[18432];
  phase4(blockIdx.x, threadIdx.x, smem, bm, T, Craw_part);
}
__global__ __launch_bounds__(NT, 2) void f5(
    const float* Craw_part, const float* bg1, const float* Wg2,
    const float* bo1, const float* Wo2, float* T2) {
  phase5(blockIdx.x, threadIdx.x, Craw_part, bg1, Wg2, bo1, Wo2, T2);
}
__global__ __launch_bounds__(NT, 2) void f6(
    const unsigned int* bm, const float* T2, const float* bg2,
    const float* bo2, float* out) {
  phase6(blockIdx.x, threadIdx.x, bm, T2, bg2, bo2, out);
}

extern "C" void kernel_launch(void* const* d_in, const int* in_sizes, int n_in,
                              void* d_out, int out_size, void* d_ws, size_t ws_size,
                              hipStream_t stream) {
  const float* node = (const float*)d_in[0];
  const float* uv = (const float*)d_in[1];
  const float* adj = (const float*)d_in[2];  // batch 0 = first 2048*2048
  const float* Wt1 = (const float*)d_in[3];
  const float* at1 = (const float*)d_in[4];
  const float* Wt2 = (const float*)d_in[5];
  const float* at2 = (const float*)d_in[6];
  const float* Wg1 = (const float*)d_in[7];
  const float* bg1 = (const float*)d_in[8];
  const float* Wg2 = (const float*)d_in[9];
  const float* bg2 = (const float*)d_in[10];
  const float* Wo1 = (const float*)d_in[11];
  const float* bo1 = (const float*)d_in[12];
  const float* Wo2 = (const float*)d_in[13];
  const float* bo2 = (const float*)d_in[14];
  float* ws = (float*)d_ws;
  float* hcol = ws;                              // 73728
  float* pack2 = ws + 73728;                     // 36864
  float4* pk1q = (float4*)(ws + 110592);         // 6*2048 float4 = 49152 f
  float* hs8 = ws + 159744;                      // 98304
  float* T = ws + 258048;                        // 65536
  float* T2 = ws + 323584;                       // 8192
  unsigned int* bm = (unsigned int*)(ws + 331776);  // 131072 u32
  float* hp_part = ws + 462848;                  // 16 * 73728 = 1179648
  float* Craw_part = ws + 1642496;               // 8 * 65536 = 524288
  float* out = (float*)d_out;

  void* args[] = {
      (void*)&adj, (void*)&bm, (void*)&node, (void*)&uv,
      (void*)&Wt1, (void*)&at1, (void*)&Wt2, (void*)&at2,
      (void*)&hcol, (void*)&pk1q, (void*)&pack2, (void*)&hs8,
      (void*)&hp_part, (void*)&Wg1, (void*)&Wo1, (void*)&T,
      (void*)&Craw_part, (void*)&bg1, (void*)&Wg2, (void*)&bo1,
      (void*)&Wo2, (void*)&T2, (void*)&bg2, (void*)&bo2, (void*)&out};
  hipError_t err = hipLaunchCooperativeKernel(
      (const void*)gat_gcn_mono, dim3(NB), dim3(NT), args, 0, stream);
  if (err != hipSuccess) {
    // Deterministic fallback: same phase bodies, 7 ordinary dispatches.
    f0<<<NB, NT, 0, stream>>>(adj, bm, node, uv, Wt1, at1, Wt2, at2,
                              hcol, pk1q, pack2);
    f1<<<NB, NT, 0, stream>>>(bm, pk1q, pack2, hcol, hs8);
    f2<<<NB, NT, 0, stream>>>(bm, pk1q, pack2, (const float4*)hs8, hp_part);
    f3<<<NB, NT, 0, stream>>>(hp_part, Wg1, Wo1, T);
    f4<<<NB, NT, 0, stream>>>(bm, T, Craw_part);
    f5<<<NB, NT, 0, stream>>>(Craw_part, bg1, Wg2, bo1, Wo2, T2);
    f6<<<NB, NT, 0, stream>>>(bm, T2, bg2, bo2, out);
  }
}

// Round 12
// 180.062 us; speedup vs baseline: 2.1319x; 2.1319x over previous
//
#include <hip/hip_runtime.h>
#include <hip/hip_bf16.h>

// GAT x2 (3 heads, E=2048, batch 0 only) + 2-layer GCN, log_softmax / leaky.
// Non-neighbor exp(-30) terms dropped (~1e-10 effect vs threshold 32).
// adj -> 512 KB bitmask; all E x E passes consume bits. No atomics (f32
// atomicAdd = uncached 16B HBM RMW, ~45us/1M, R6). Split-K via plain-stored
// partials merged inline in consumers (adequate grids). NO cooperative
// grid.sync (measured ~30us each on 8-XCD MI355X, R11). 7 dispatches.
// Best-measured structure (R7, 183.6us) + k0/k1 fused into k01.

// ---------------------------------------------------------------------------
// K01: blocks 0..511: bitmask (4 rows each). blocks 512..559: features.
__global__ __launch_bounds__(256) void k01(
    const float* __restrict__ adj0, unsigned int* __restrict__ bm,
    const float* __restrict__ node, const float* __restrict__ uv,
    const float* __restrict__ Wt1, const float* __restrict__ at1,
    const float* __restrict__ Wt2, const float* __restrict__ at2,
    float* __restrict__ hcol, float* __restrict__ pack1, float* __restrict__ pack2) {
  int b = blockIdx.x;
  if (b < 512) {
    int lane = threadIdx.x & 63, w = threadIdx.x >> 6;
    int row = b * 4 + w;
    const float* arow = adj0 + (size_t)row * 2048;
#pragma unroll 4
    for (int it = 0; it < 32; ++it) {
      float v = arow[it * 64 + lane];
      unsigned long long mask = __ballot(v == 1.0f);
      if (lane == 0) bm[row * 64 + it * 2] = (unsigned int)mask;
      else if (lane == 32) bm[row * 64 + it * 2 + 1] = (unsigned int)(mask >> 32);
    }
    return;
  }
  __shared__ float sW[192];
  __shared__ float sA[12];
  int fb = b - 512;                 // 0..47
  int g = fb / 24;
  int h = (fb / 8) % 3;
  int e = (fb % 8) * 256 + threadIdx.x;
  const float* W = (g ? Wt2 : Wt1) + h * 192;
  const float* A = (g ? at2 : at1) + h * 12;
  const float* x = (g ? uv : node) + e * 32;
  if (threadIdx.x < 192) sW[threadIdx.x] = W[threadIdx.x];
  if (threadIdx.x < 12) sA[threadIdx.x] = A[threadIdx.x];
  __syncthreads();
  float xv[32];
#pragma unroll
  for (int i = 0; i < 32; ++i) xv[i] = x[i];
  float hv[6];
#pragma unroll
  for (int d = 0; d < 6; ++d) hv[d] = 0.f;
#pragma unroll
  for (int i = 0; i < 32; ++i)
#pragma unroll
    for (int d = 0; d < 6; ++d) hv[d] += xv[i] * sW[i * 6 + d];
  float e1 = 0.f, e2 = 0.f;
#pragma unroll
  for (int d = 0; d < 6; ++d) {
    e1 += hv[d] * sA[d];
    e2 += hv[d] * sA[6 + d];
  }
  int c = g * 3 + h;
#pragma unroll
  for (int d = 0; d < 6; ++d) hcol[(c * 6 + d) * 2048 + e] = hv[d];
  pack1[c * 2048 + e] = e1;
  pack1[(6 + c) * 2048 + e] = __expf(e1);
  pack1[(12 + c) * 2048 + e] = __expf(0.2f * e1);
  pack2[c * 2048 + e] = e2;
  pack2[(6 + c) * 2048 + e] = __expf(e2);
  pack2[(12 + c) * 2048 + e] = __expf(0.2f * e2);
}

// ---------------------------------------------------------------------------
// K2: invrs[c][i] = 1 / sum_j w(i,j,c), w = bit * (pos? p1*p2 : q1*q2).
// Block 384 (wave = comp c), 8 rows per block, lanes sweep j 4-at-a-time.
__global__ __launch_bounds__(384) void k2_rowsum(
    const unsigned int* __restrict__ bm, const float* __restrict__ pack1,
    const float* __restrict__ pack2, float* __restrict__ invrs) {
  int tid = threadIdx.x;
  int c = tid >> 6, lane = tid & 63;
  int i0 = blockIdx.x * 8;
  const float4* p2_4 = (const float4*)pack2;
  float e1r[8], p1r[8], q1r[8], sum[8];
#pragma unroll
  for (int r = 0; r < 8; ++r) {
    e1r[r] = pack1[c * 2048 + i0 + r];
    p1r[r] = pack1[(6 + c) * 2048 + i0 + r];
    q1r[r] = pack1[(12 + c) * 2048 + i0 + r];
    sum[r] = 0.f;
  }
  int sh = (lane & 7) * 4;
#pragma unroll
  for (int it = 0; it < 8; ++it) {
    int j4 = it * 64 + lane;  // float4 index; covers j = 4*j4 .. +3
    float4 e2 = p2_4[c * 512 + j4];
    float4 p2 = p2_4[(6 + c) * 512 + j4];
    float4 q2 = p2_4[(12 + c) * 512 + j4];
    int wbase = it * 8 + (lane >> 3);
    float abx, aby, abz, abw;
#pragma unroll
    for (int r = 0; r < 8; ++r) {
      unsigned int wd = bm[(i0 + r) * 64 + wbase] >> sh;
      { float e = e1r[r] + e2.x; bool p = e > 0.f;
        abx = (p ? p1r[r] : q1r[r]) * (p ? p2.x : q2.x); }
      { float e = e1r[r] + e2.y; bool p = e > 0.f;
        aby = (p ? p1r[r] : q1r[r]) * (p ? p2.y : q2.y); }
      { float e = e1r[r] + e2.z; bool p = e > 0.f;
        abz = (p ? p1r[r] : q1r[r]) * (p ? p2.z : q2.z); }
      { float e = e1r[r] + e2.w; bool p = e > 0.f;
        abw = (p ? p1r[r] : q1r[r]) * (p ? p2.w : q2.w); }
      float s = ((wd & 1u) ? abx : 0.f) + ((wd & 2u) ? aby : 0.f) +
                ((wd & 4u) ? abz : 0.f) + ((wd & 8u) ? abw : 0.f);
      sum[r] += s;
    }
  }
#pragma unroll
  for (int r = 0; r < 8; ++r) {
#pragma unroll
    for (int off = 32; off > 0; off >>= 1) sum[r] += __shfl_down(sum[r], off);
  }
  if (lane == 0) {
#pragma unroll
    for (int r = 0; r < 8; ++r) invrs[c * 2048 + i0 + r] = 1.0f / sum[r];
  }
}

// ---------------------------------------------------------------------------
// K3: hp_part[s][k][j] = sum_{i in split s} w(i,j,c) * (h[i,k]*invrs[c][i]).
// Block 384 (wave = comp c), 2 j per thread. Grid (16 j-tiles of 128,
// 16 i-splits of 128; 2 staged 64-i rounds). Plain stores (no atomics).
__global__ __launch_bounds__(384) void k3_hprime(
    const unsigned int* __restrict__ bm, const float* __restrict__ hcol,
    const float* __restrict__ pack1, const float* __restrict__ pack2,
    const float* __restrict__ invrs, float* __restrict__ hp_part) {
  __shared__ float4 sPack[6 * 64];       // e1, p1, q1, 0 per (c, ii)
  __shared__ float sHS[6 * 64 * 8];      // scaled h, 6 used + 2 pad
  __shared__ unsigned int sM[64 * 4];    // mask words for 64 i x 128 j
  float4* sHS4 = (float4*)sHS;
  int tid = threadIdx.x;
  int c6 = tid >> 6, jl = tid & 63;
  int j0 = blockIdx.x * 128;
  int jA = j0 + jl, jB = jA + 64;
  float e2A = pack2[c6 * 2048 + jA];
  float p2A = pack2[(6 + c6) * 2048 + jA];
  float q2A = pack2[(12 + c6) * 2048 + jA];
  float e2B = pack2[c6 * 2048 + jB];
  float p2B = pack2[(6 + c6) * 2048 + jB];
  float q2B = pack2[(12 + c6) * 2048 + jB];
  float aA0 = 0.f, aA1 = 0.f, aA2 = 0.f, aA3 = 0.f, aA4 = 0.f, aA5 = 0.f;
  float aB0 = 0.f, aB1 = 0.f, aB2 = 0.f, aB3 = 0.f, aB4 = 0.f, aB5 = 0.f;
  int hi = jl >> 5;
  int shj = jl & 31;
  int ibeg = blockIdx.y * 128;
  for (int i0 = ibeg; i0 < ibeg + 128; i0 += 64) {
    __syncthreads();
    {
      int cc = c6, ii = jl;
      float e1 = pack1[cc * 2048 + i0 + ii];
      float p1 = pack1[(6 + cc) * 2048 + i0 + ii];
      float q1 = pack1[(12 + cc) * 2048 + i0 + ii];
      sPack[cc * 64 + ii] = make_float4(e1, p1, q1, 0.f);
      float iv = invrs[cc * 2048 + i0 + ii];
#pragma unroll
      for (int d = 0; d < 6; ++d)
        sHS[(cc * 64 + ii) * 8 + d] = hcol[(cc * 6 + d) * 2048 + i0 + ii] * iv;
      sHS[(cc * 64 + ii) * 8 + 6] = 0.f;
      sHS[(cc * 64 + ii) * 8 + 7] = 0.f;
    }
    if (tid < 256) sM[tid] = bm[(size_t)(i0 + (tid >> 2)) * 64 + (j0 >> 5) + (tid & 3)];
    __syncthreads();
#pragma unroll 8
    for (int ii = 0; ii < 64; ++ii) {
      float4 pk = sPack[c6 * 64 + ii];
      float4 h0 = sHS4[(c6 * 64 + ii) * 2];
      float4 h1 = sHS4[(c6 * 64 + ii) * 2 + 1];
      unsigned int wdA = sM[ii * 4 + hi];
      unsigned int wdB = sM[ii * 4 + 2 + hi];
      {
        float e = pk.x + e2A; bool p = e > 0.f;
        float ab = (p ? pk.y : pk.z) * (p ? p2A : q2A);
        float wgt = ((wdA >> shj) & 1u) ? ab : 0.f;
        aA0 += wgt * h0.x; aA1 += wgt * h0.y; aA2 += wgt * h0.z;
        aA3 += wgt * h0.w; aA4 += wgt * h1.x; aA5 += wgt * h1.y;
      }
      {
        float e = pk.x + e2B; bool p = e > 0.f;
        float ab = (p ? pk.y : pk.z) * (p ? p2B : q2B);
        float wgt = ((wdB >> shj) & 1u) ? ab : 0.f;
        aB0 += wgt * h0.x; aB1 += wgt * h0.y; aB2 += wgt * h0.z;
        aB3 += wgt * h0.w; aB4 += wgt * h1.x; aB5 += wgt * h1.y;
      }
    }
  }
  float* hp = hp_part + (size_t)blockIdx.y * 73728;
  int kb = c6 * 6;
  hp[(kb + 0) * 2048 + jA] = aA0;
  hp[(kb + 1) * 2048 + jA] = aA1;
  hp[(kb + 2) * 2048 + jA] = aA2;
  hp[(kb + 3) * 2048 + jA] = aA3;
  hp[(kb + 4) * 2048 + jA] = aA4;
  hp[(kb + 5) * 2048 + jA] = aA5;
  hp[(kb + 0) * 2048 + jB] = aB0;
  hp[(kb + 1) * 2048 + jB] = aB1;
  hp[(kb + 2) * 2048 + jB] = aB2;
  hp[(kb + 3) * 2048 + jB] = aB3;
  hp[(kb + 4) * 2048 + jB] = aB4;
  hp[(kb + 5) * 2048 + jB] = aB5;
}

// ---------------------------------------------------------------------------
// K4: merge 16 hp partials -> elu -> T[j][32] = {hcY@Wg1, hcO@Wo1}.
// 16 j per block, grid 128.
__global__ __launch_bounds__(256) void k4_T(
    const float* __restrict__ hp_part, const float* __restrict__ Wg1,
    const float* __restrict__ Wo1, float* __restrict__ T) {
  __shared__ float sHP[16 * 37];
  __shared__ float sWg[288], sWo[288];
  int tid = threadIdx.x;
  int j0 = blockIdx.x * 16;
  for (int idx = tid; idx < 288; idx += 256) {
    sWg[idx] = Wg1[idx];
    sWo[idx] = Wo1[idx];
  }
  for (int idx = tid; idx < 576; idx += 256) {
    int r = idx >> 4, jl = idx & 15;
    float s = 0.f;
#pragma unroll
    for (int sp = 0; sp < 16; ++sp)
      s += hp_part[(size_t)sp * 73728 + r * 2048 + j0 + jl];
    sHP[jl * 37 + r] = s;
  }
  __syncthreads();
  int jl = tid & 15, wq = tid >> 4;  // 16 slots: gat(2) x colpair(8)
  int gat = wq >> 3;
  int c0 = (wq & 7) * 2;
  const float* Wp = gat ? sWo : sWg;
  float a0 = 0.f, a1 = 0.f;
#pragma unroll
  for (int r = 0; r < 18; ++r) {
    float x = sHP[jl * 37 + gat * 18 + r];
    float hc = x > 0.f ? x : __expf(x) - 1.f;
    a0 += hc * Wp[r * 16 + c0];
    a1 += hc * Wp[r * 16 + c0 + 1];
  }
  T[(j0 + jl) * 32 + gat * 16 + c0] = a0;
  T[(j0 + jl) * 32 + gat * 16 + c0 + 1] = a1;
}

// ---------------------------------------------------------------------------
// K5: Craw_part[s][r][c] = sum_{k in split s} bit(r,k) * T[k][c].
// Grid (32 row-tiles of 64, 16 k-splits of 128). Plain float4 stores.
__global__ __launch_bounds__(256) void k5_gcn1(
    const unsigned int* __restrict__ bm, const float* __restrict__ T,
    float* __restrict__ Craw_part) {
  __shared__ unsigned int sM[64 * 4];
  __shared__ float4 sT4[128 * 8];
  const float4* T4 = (const float4*)T;
  int tid = threadIdx.x;
  int rl = tid & 31, cg = tid >> 5;
  int i0 = blockIdx.x * 64;
  int k0 = blockIdx.y * 128;
  sM[tid] = bm[(size_t)(i0 + (tid >> 2)) * 64 + (k0 >> 5) + (tid & 3)];
  for (int idx = tid; idx < 1024; idx += 256) sT4[idx] = T4[k0 * 8 + idx];
  __syncthreads();
  float a0x = 0.f, a0y = 0.f, a0z = 0.f, a0w = 0.f;
  float a1x = 0.f, a1y = 0.f, a1z = 0.f, a1w = 0.f;
#pragma unroll
  for (int wi = 0; wi < 4; ++wi) {
    unsigned int wA = sM[rl * 4 + wi];
    unsigned int wB = sM[(rl + 32) * 4 + wi];
#pragma unroll 16
    for (int kb = 0; kb < 32; ++kb) {
      float4 t = sT4[(wi * 32 + kb) * 8 + cg];
      float mA = (float)((wA >> kb) & 1u);
      float mB = (float)((wB >> kb) & 1u);
      a0x += mA * t.x; a0y += mA * t.y; a0z += mA * t.z; a0w += mA * t.w;
      a1x += mB * t.x; a1y += mB * t.y; a1z += mB * t.z; a1w += mB * t.w;
    }
  }
  float* base = Craw_part + (size_t)blockIdx.y * 65536;
  *(float4*)&base[(i0 + rl) * 32 + cg * 4] = make_float4(a0x, a0y, a0z, a0w);
  *(float4*)&base[(i0 + rl + 32) * 32 + cg * 4] = make_float4(a1x, a1y, a1z, a1w);
}

// ---------------------------------------------------------------------------
// K6: merge 16 Craw partials, +bias, relu, @Wg2/@Wo2 -> T2[j][4]. Grid 256.
__global__ __launch_bounds__(256) void k6_T2(
    const float* __restrict__ Craw_part, const float* __restrict__ bg1,
    const float* __restrict__ Wg2, const float* __restrict__ bo1,
    const float* __restrict__ Wo2, float* __restrict__ T2) {
  int tid = threadIdx.x;
  int wave = tid >> 6, lane = tid & 63;
  int j = blockIdx.x * 8 + wave * 2 + (lane >> 5);
  int cl = lane & 31;
  int gat = cl >> 4, cc = cl & 15;
  float x = 0.f;
#pragma unroll
  for (int sp = 0; sp < 16; ++sp) x += Craw_part[(size_t)sp * 65536 + j * 32 + cl];
  x += gat ? bo1[cc] : bg1[cc];
  x = x > 0.f ? x : 0.f;
  float wa = gat ? Wo2[cc * 2 + 0] : Wg2[cc * 2 + 0];
  float wb = gat ? Wo2[cc * 2 + 1] : Wg2[cc * 2 + 1];
  float pa = x * wa, pb = x * wb;
#pragma unroll
  for (int m = 8; m > 0; m >>= 1) {
    pa += __shfl_xor(pa, m);
    pb += __shfl_xor(pb, m);
  }
  if (cc == 0) {
    T2[j * 4 + gat * 2 + 0] = pa;
    T2[j * 4 + gat * 2 + 1] = pb;
  }
}

// ---------------------------------------------------------------------------
// K7: final out = a0 @ T2 (+bias), log_softmax(axis=1) + leaky(0.01).
// Wave per row, grid 512.
__global__ __launch_bounds__(256) void k7_final(
    const unsigned int* __restrict__ bm, const float* __restrict__ T2,
    const float* __restrict__ bg2, const float* __restrict__ bo2,
    float* __restrict__ out) {
  int tid = threadIdx.x;
  int lane = tid & 63, w = tid >> 6;
  int r = blockIdx.x * 4 + w;
  const float4* T24 = (const float4*)T2;
  float4 acc = make_float4(0.f, 0.f, 0.f, 0.f);
  int sh = lane & 31;
#pragma unroll 8
  for (int it = 0; it < 32; ++it) {
    int k = it * 64 + lane;
    unsigned int wd = bm[r * 64 + it * 2 + (lane >> 5)];
    float m = (float)((wd >> sh) & 1u);
    float4 t = T24[k];
    acc.x += m * t.x;
    acc.y += m * t.y;
    acc.z += m * t.z;
    acc.w += m * t.w;
  }
#pragma unroll
  for (int off = 32; off > 0; off >>= 1) {
    acc.x += __shfl_down(acc.x, off);
    acc.y += __shfl_down(acc.y, off);
    acc.z += __shfl_down(acc.z, off);
    acc.w += __shfl_down(acc.w, off);
  }
  if (lane == 0) {
    float y0 = acc.x + bg2[0], y1 = acc.y + bg2[1];
    float m = fmaxf(y0, y1);
    float ls = m + logf(__expf(y0 - m) + __expf(y1 - m));
    out[r * 2 + 0] = y0 - ls;
    out[r * 2 + 1] = y1 - ls;
    float o0 = acc.z + bo2[0], o1 = acc.w + bo2[1];
    out[4096 + r * 2 + 0] = o0 > 0.f ? o0 : 0.01f * o0;
    out[4096 + r * 2 + 1] = o1 > 0.f ? o1 : 0.01f * o1;
  }
}

extern "C" void kernel_launch(void* const* d_in, const int* in_sizes, int n_in,
                              void* d_out, int out_size, void* d_ws, size_t ws_size,
                              hipStream_t stream) {
  const float* node = (const float*)d_in[0];
  const float* uv = (const float*)d_in[1];
  const float* adj = (const float*)d_in[2];  // batch 0 = first 2048*2048
  const float* Wt1 = (const float*)d_in[3];
  const float* at1 = (const float*)d_in[4];
  const float* Wt2 = (const float*)d_in[5];
  const float* at2 = (const float*)d_in[6];
  const float* Wg1 = (const float*)d_in[7];
  const float* bg1 = (const float*)d_in[8];
  const float* Wg2 = (const float*)d_in[9];
  const float* bg2 = (const float*)d_in[10];
  const float* Wo1 = (const float*)d_in[11];
  const float* bo1 = (const float*)d_in[12];
  const float* Wo2 = (const float*)d_in[13];
  const float* bo2 = (const float*)d_in[14];
  float* ws = (float*)d_ws;
  float* hcol = ws;                          // 73728
  float* pack1 = ws + 73728;                 // 36864
  float* pack2 = ws + 110592;                // 36864
  float* invrs = ws + 147456;                // 12288
  float* T = ws + 159744;                    // 65536
  float* T2 = ws + 225280;                   // 8192
  unsigned int* bm = (unsigned int*)(ws + 233472);  // 131072 u32 = 512 KB
  float* hp_part = ws + 364544;              // 16 * 73728 = 1179648
  float* Craw_part = ws + 1544192;           // 16 * 65536 = 1048576
  float* out = (float*)d_out;

  k01<<<560, 256, 0, stream>>>(adj, bm, node, uv, Wt1, at1, Wt2, at2,
                               hcol, pack1, pack2);
  k2_rowsum<<<256, 384, 0, stream>>>(bm, pack1, pack2, invrs);
  k3_hprime<<<dim3(16, 16), 384, 0, stream>>>(bm, hcol, pack1, pack2, invrs, hp_part);
  k4_T<<<128, 256, 0, stream>>>(hp_part, Wg1, Wo1, T);
  k5_gcn1<<<dim3(32, 16), 256, 0, stream>>>(bm, T, Craw_part);
  k6_T2<<<256, 256, 0, stream>>>(Craw_part, bg1, Wg2, bo1, Wo2, T2);
  k7_final<<<512, 256, 0, stream>>>(bm, T2, bg2, bo2, out);
}